// Round 6
// baseline (668.559 us; speedup 1.0000x reference)
//
#include <hip/hip_runtime.h>
#include <hip/hip_bf16.h>
#include <math.h>

#define NN 8192
#define DD 512
#define INV_T 14.285714285714286f   // 1/0.07 ; also the logits_max (diagonal) value

typedef __attribute__((ext_vector_type(8))) short s16x8;  // 8 bf16 = 4 VGPRs
typedef __attribute__((ext_vector_type(4))) float f32x4;
typedef __attribute__((ext_vector_type(4))) int   i32x4;

__device__ __forceinline__ unsigned short f32_to_bf16(float f) {
  unsigned int u = __float_as_uint(f);
  u += 0x7FFFu + ((u >> 16) & 1u);   // round-to-nearest-even
  return (unsigned short)(u >> 16);
}

// ---------------- Kernel A: normalize rows, emit bf16 ----------------
__global__ __launch_bounds__(256) void normalize_kernel(const float* __restrict__ f,
                                                        unsigned short* __restrict__ fnb) {
  const int wave = threadIdx.x >> 6;
  const int lane = threadIdx.x & 63;
  const int row  = blockIdx.x * 4 + wave;
  const float* src = f + (size_t)row * DD + lane * 8;
  float4 v0 = *(const float4*)src;
  float4 v1 = *(const float4*)(src + 4);
  float ss = v0.x*v0.x + v0.y*v0.y + v0.z*v0.z + v0.w*v0.w
           + v1.x*v1.x + v1.y*v1.y + v1.z*v1.z + v1.w*v1.w;
  #pragma unroll
  for (int o = 32; o; o >>= 1) ss += __shfl_xor(ss, o);
  const float r = 1.0f / fmaxf(sqrtf(ss), 1e-8f);
  ushort4 a, b;
  a.x = f32_to_bf16(v0.x * r); a.y = f32_to_bf16(v0.y * r);
  a.z = f32_to_bf16(v0.z * r); a.w = f32_to_bf16(v0.w * r);
  b.x = f32_to_bf16(v1.x * r); b.y = f32_to_bf16(v1.y * r);
  b.z = f32_to_bf16(v1.z * r); b.w = f32_to_bf16(v1.w * r);
  unsigned short* dst = fnb + (size_t)row * DD + lane * 8;
  *(ushort4*)dst = a;
  *(ushort4*)(dst + 4) = b;
}

// ---------------- Kernel B: fused tile, mask-aligned MFMA column permutation ----------------
// 128x128 tile per block, 4 waves each 64x64 (4x4 of 16x16x32 bf16 MFMA).
// B-fragment for tile nt, lane n loads fnb row J + wn*64 + 4*n + nt, so lane
// c16's four nt-accumulators cover sim columns 4*c16..4*c16+3 -- exactly one
// int4 of the mask row. Epilogue does flat coalesced int4 mask loads straight
// into FMAs: no ballot, no LDS, no barriers anywhere in the kernel.
__global__ __launch_bounds__(256) void fused_kernel(const unsigned short* __restrict__ fnb,
                                                    const int* __restrict__ posm,
                                                    const int* __restrict__ negm,
                                                    float* __restrict__ Spos,
                                                    float* __restrict__ Sneg,
                                                    float* __restrict__ Pcnt) {
  // decode compact triangular block id -> (bi, bj), bi <= bj, 64x64 block grid
  const int bid = blockIdx.x;
  int bi = (int)(64.5 - sqrt(64.5 * 64.5 - 2.0 * (double)bid));
  while (64 * bi - bi * (bi - 1) / 2 > bid) --bi;
  while (64 * (bi + 1) - (bi + 1) * bi / 2 <= bid) ++bi;
  const int bj = bi + (bid - (64 * bi - bi * (bi - 1) / 2));
  const int I = bi * 128;
  const int J = bj * 128;
  const bool offdiag = (bi != bj);

  const int tid  = threadIdx.x;
  const int wave = tid >> 6;
  const int lane = tid & 63;
  const int wm = wave >> 1;            // 0..1 row half
  const int wn = wave & 1;             // 0..1 col half
  const int q   = lane >> 4;           // 0..3
  const int c16 = lane & 15;           // 0..15

  // ---- GEMM: fragments direct from global fnb (L2/L3-resident) ----
  f32x4 acc[4][4];
  const f32x4 z4 = {0.f, 0.f, 0.f, 0.f};
  #pragma unroll
  for (int mt = 0; mt < 4; ++mt)
    #pragma unroll
    for (int nt = 0; nt < 4; ++nt) acc[mt][nt] = z4;

  const unsigned short* aP[4];
  const unsigned short* bP[4];
  #pragma unroll
  for (int t = 0; t < 4; ++t) {
    aP[t] = fnb + (size_t)(I + wm * 64 + t * 16 + c16) * DD + q * 8;       // rows: MFMA-natural
    bP[t] = fnb + (size_t)(J + wn * 64 + 4 * c16 + t) * DD + q * 8;       // cols: int4-natural
  }
  s16x8 aF[2][4], bF[2][4];
  #pragma unroll
  for (int t = 0; t < 4; ++t) {
    aF[0][t] = *(const s16x8*)aP[t];
    bF[0][t] = *(const s16x8*)bP[t];
  }
  #pragma unroll 2
  for (int kk = 0; kk < DD / 32; ++kk) {
    const int cur = kk & 1, nxt = cur ^ 1;
    if (kk < DD / 32 - 1) {
      const int off = (kk + 1) * 32;
      #pragma unroll
      for (int t = 0; t < 4; ++t) {
        aF[nxt][t] = *(const s16x8*)(aP[t] + off);
        bF[nxt][t] = *(const s16x8*)(bP[t] + off);
      }
    }
    #pragma unroll
    for (int mt = 0; mt < 4; ++mt)
      #pragma unroll
      for (int nt = 0; nt < 4; ++nt)
        acc[mt][nt] = __builtin_amdgcn_mfma_f32_16x16x32_bf16(aF[cur][mt], bF[cur][nt], acc[mt][nt], 0, 0, 0);
  }

  // ---- epilogue ----
  // acc[mt][nt][r] = sim[row = I + wm*64 + mt*16 + q*4 + r][col = J + wn*64 + 4*c16 + nt]
  // exp in place
  #pragma unroll
  for (int mt = 0; mt < 4; ++mt)
    #pragma unroll
    for (int nt = 0; nt < 4; ++nt)
      #pragma unroll
      for (int r = 0; r < 4; ++r)
        acc[mt][nt][r] = __expf(acc[mt][nt][r] * INV_T - INV_T);

  const bool hasdiag = (bi == bj) && (wm == wn);
  const int cb = wn * 64 + 4 * c16;            // local col base (this lane's int4)

  // direct pass: rows I.., cols J.. ; one int4 per (mt, r) per mask
  #pragma unroll
  for (int mt = 0; mt < 4; ++mt) {
    const int rl = wm * 64 + mt * 16 + q * 4;  // local row base
    i32x4 pv[4], nv[4];
    #pragma unroll
    for (int r = 0; r < 4; ++r) {
      const size_t off = (size_t)(I + rl + r) * NN + J + cb;
      pv[r] = __builtin_nontemporal_load((const i32x4*)(posm + off));
      nv[r] = __builtin_nontemporal_load((const i32x4*)(negm + off));
    }
    float dsp[4], dsn[4], dpc[4];
    #pragma unroll
    for (int r = 0; r < 4; ++r) { dsp[r] = 0.f; dsn[r] = 0.f; dpc[r] = 0.f; }
    #pragma unroll
    for (int r = 0; r < 4; ++r) {
      #pragma unroll
      for (int nt = 0; nt < 4; ++nt) {
        float pf = (float)pv[r][nt];
        float nf = (float)nv[r][nt];
        if (hasdiag && (rl + r == cb + nt)) { pf = 0.f; nf = 0.f; }  // self-contrast diag
        const float e = acc[mt][nt][r];
        dsp[r] = fmaf(e, pf, dsp[r]);
        dsn[r] = fmaf(e, nf, dsn[r]);
        dpc[r] += pf;
      }
    }
    #pragma unroll
    for (int r = 0; r < 4; ++r) {
      float a = dsp[r], b = dsn[r], p = dpc[r];
      #pragma unroll
      for (int o = 1; o <= 8; o <<= 1) {
        a += __shfl_xor(a, o);
        b += __shfl_xor(b, o);
        p += __shfl_xor(p, o);
      }
      if (c16 == 0) {
        const int row = I + rl + r;
        atomicAdd(&Spos[row], a);
        atomicAdd(&Sneg[row], b);
        atomicAdd(&Pcnt[row], p);
      }
    }
  }

  // transposed pass: sim(col,row) == sim(row,col); rows J.., cols I..
  if (offdiag) {
    #pragma unroll
    for (int nt = 0; nt < 4; ++nt) {
      const int trow = J + cb + nt;            // global row in transposed pass
      i32x4 pv[4], nv[4];
      #pragma unroll
      for (int mt = 0; mt < 4; ++mt) {
        const size_t off = (size_t)trow * NN + I + wm * 64 + mt * 16 + q * 4;
        pv[mt] = __builtin_nontemporal_load((const i32x4*)(posm + off));
        nv[mt] = __builtin_nontemporal_load((const i32x4*)(negm + off));
      }
      float ts = 0.f, tn = 0.f, tp = 0.f;
      #pragma unroll
      for (int mt = 0; mt < 4; ++mt) {
        #pragma unroll
        for (int r = 0; r < 4; ++r) {
          const float pf = (float)pv[mt][r];
          const float nf = (float)nv[mt][r];
          const float e  = acc[mt][nt][r];
          ts = fmaf(e, pf, ts);
          tn = fmaf(e, nf, tn);
          tp += pf;
        }
      }
      ts += __shfl_xor(ts, 16); ts += __shfl_xor(ts, 32);
      tn += __shfl_xor(tn, 16); tn += __shfl_xor(tn, 32);
      tp += __shfl_xor(tp, 16); tp += __shfl_xor(tp, 32);
      if (q == 0) {
        atomicAdd(&Spos[trow], ts);
        atomicAdd(&Sneg[trow], tn);
        atomicAdd(&Pcnt[trow], tp);
      }
    }
  }
}

// ---------------- Kernel C: finalize ----------------
__global__ __launch_bounds__(256) void finalize_kernel(const float* __restrict__ Spos,
                                                       const float* __restrict__ Sneg,
                                                       const float* __restrict__ Pcnt,
                                                       float* __restrict__ out) {
  float local = 0.f;
  for (int i = threadIdx.x; i < NN; i += 256) {
    const float sp = Spos[i], sn = Sneg[i], pc = Pcnt[i];
    const float card = (pc == 0.f) ? 1.f : pc;
    // loss_i = -(sp - log(sn)*pc)/card
    local += (logf(sn) * pc - sp) / card;
  }
  #pragma unroll
  for (int o = 32; o; o >>= 1) local += __shfl_xor(local, o);
  __shared__ float red[4];
  if ((threadIdx.x & 63) == 0) red[threadIdx.x >> 6] = local;
  __syncthreads();
  if (threadIdx.x == 0)
    out[0] = (red[0] + red[1] + red[2] + red[3]) * (1.0f / (float)NN);
}

extern "C" void kernel_launch(void* const* d_in, const int* in_sizes, int n_in,
                              void* d_out, int out_size, void* d_ws, size_t ws_size,
                              hipStream_t stream) {
  const float* feat = (const float*)d_in[0];
  const int* posm   = (const int*)d_in[1];
  const int* negm   = (const int*)d_in[2];
  float* out = (float*)d_out;

  char* ws = (char*)d_ws;
  unsigned short* fnb = (unsigned short*)ws;                 // 8 MB
  float* Spos = (float*)(ws + (size_t)8 * 1024 * 1024);
  float* Sneg = Spos + NN;
  float* Pcnt = Sneg + NN;

  hipMemsetAsync(Spos, 0, 3 * NN * sizeof(float), stream);
  normalize_kernel<<<NN / 4, 256, 0, stream>>>(feat, fnb);
  fused_kernel<<<2080, 256, 0, stream>>>(fnb, posm, negm, Spos, Sneg, Pcnt);
  finalize_kernel<<<1, 256, 0, stream>>>(Spos, Sneg, Pcnt, out);
}

// Round 7
// 622.162 us; speedup vs baseline: 1.0746x; 1.0746x over previous
//
#include <hip/hip_runtime.h>
#include <hip/hip_bf16.h>
#include <math.h>

#define NN 8192
#define DD 512
#define INV_T 14.285714285714286f   // 1/0.07 ; also the logits_max (diagonal) value

typedef __attribute__((ext_vector_type(8))) short s16x8;  // 8 bf16 = 4 VGPRs
typedef __attribute__((ext_vector_type(4))) float f32x4;
typedef __attribute__((ext_vector_type(4))) int   i32x4;

__device__ __forceinline__ unsigned short f32_to_bf16(float f) {
  unsigned int u = __float_as_uint(f);
  u += 0x7FFFu + ((u >> 16) & 1u);   // round-to-nearest-even
  return (unsigned short)(u >> 16);
}

// ---------------- Kernel A: normalize rows, emit bf16 ----------------
__global__ __launch_bounds__(256) void normalize_kernel(const float* __restrict__ f,
                                                        unsigned short* __restrict__ fnb) {
  const int wave = threadIdx.x >> 6;
  const int lane = threadIdx.x & 63;
  const int row  = blockIdx.x * 4 + wave;
  const float* src = f + (size_t)row * DD + lane * 8;
  float4 v0 = *(const float4*)src;
  float4 v1 = *(const float4*)(src + 4);
  float ss = v0.x*v0.x + v0.y*v0.y + v0.z*v0.z + v0.w*v0.w
           + v1.x*v1.x + v1.y*v1.y + v1.z*v1.z + v1.w*v1.w;
  #pragma unroll
  for (int o = 32; o; o >>= 1) ss += __shfl_xor(ss, o);
  const float r = 1.0f / fmaxf(sqrtf(ss), 1e-8f);
  ushort4 a, b;
  a.x = f32_to_bf16(v0.x * r); a.y = f32_to_bf16(v0.y * r);
  a.z = f32_to_bf16(v0.z * r); a.w = f32_to_bf16(v0.w * r);
  b.x = f32_to_bf16(v1.x * r); b.y = f32_to_bf16(v1.y * r);
  b.z = f32_to_bf16(v1.z * r); b.w = f32_to_bf16(v1.w * r);
  unsigned short* dst = fnb + (size_t)row * DD + lane * 8;
  *(ushort4*)dst = a;
  *(ushort4*)(dst + 4) = b;
}

// ---------------- Kernel B: fused tile, LDS-accumulated epilogue ----------------
// 128x128 tile per block, 4 waves each 64x64 (4x4 of 16x16x32 bf16 MFMA).
// B-fragment for tile nt, lane n loads fnb row J + wn*64 + 4*n + nt, so lane
// c16's four nt-accumulators cover sim columns 4*c16..4*c16+3 -- one int4 of
// mask per (row, lane). KEY CHANGE vs R6: no global atomics inside the
// epilogue -- partial sums go to LDS via ds_add_f32 (lgkmcnt, not vmcnt), so
// mask loads never s_waitcnt behind an atomic's HBM round-trip. One batch of
// global atomics at kernel end.
__global__ __launch_bounds__(256, 2) void fused_kernel(const unsigned short* __restrict__ fnb,
                                                       const int* __restrict__ posm,
                                                       const int* __restrict__ negm,
                                                       float* __restrict__ Spos,
                                                       float* __restrict__ Sneg,
                                                       float* __restrict__ Pcnt) {
  // decode compact triangular block id -> (bi, bj), bi <= bj, 64x64 block grid
  const int bid = blockIdx.x;
  int bi = (int)(64.5 - sqrt(64.5 * 64.5 - 2.0 * (double)bid));
  while (64 * bi - bi * (bi - 1) / 2 > bid) --bi;
  while (64 * (bi + 1) - (bi + 1) * bi / 2 <= bid) ++bi;
  const int bj = bi + (bid - (64 * bi - bi * (bi - 1) / 2));
  const int I = bi * 128;
  const int J = bj * 128;
  const bool offdiag = (bi != bj);

  const int tid  = threadIdx.x;
  const int wave = tid >> 6;
  const int lane = tid & 63;
  const int wm = wave >> 1;            // 0..1 row half
  const int wn = wave & 1;             // 0..1 col half
  const int q   = lane >> 4;           // 0..3
  const int c16 = lane & 15;           // 0..15

  // per-row partial sums: [0]=direct (I-panel rows), [1]=transposed (J-panel)
  // [row][0]=Spos, [1]=Sneg, [2]=Pcnt
  __shared__ float sacc[2][128][3];
  for (int t = tid; t < 2 * 128 * 3; t += 256) ((float*)sacc)[t] = 0.f;

  // ---- GEMM: fragments direct from global fnb (L2/L3-resident) ----
  f32x4 acc[4][4];
  const f32x4 z4 = {0.f, 0.f, 0.f, 0.f};
  #pragma unroll
  for (int mt = 0; mt < 4; ++mt)
    #pragma unroll
    for (int nt = 0; nt < 4; ++nt) acc[mt][nt] = z4;

  const unsigned short* aP[4];
  const unsigned short* bP[4];
  #pragma unroll
  for (int t = 0; t < 4; ++t) {
    aP[t] = fnb + (size_t)(I + wm * 64 + t * 16 + c16) * DD + q * 8;   // rows: MFMA-natural
    bP[t] = fnb + (size_t)(J + wn * 64 + 4 * c16 + t) * DD + q * 8;    // cols: int4-natural
  }
  s16x8 aF[2][4], bF[2][4];
  #pragma unroll
  for (int t = 0; t < 4; ++t) {
    aF[0][t] = *(const s16x8*)aP[t];
    bF[0][t] = *(const s16x8*)bP[t];
  }
  #pragma unroll 2
  for (int kk = 0; kk < DD / 32; ++kk) {
    const int cur = kk & 1, nxt = cur ^ 1;
    if (kk < DD / 32 - 1) {
      const int off = (kk + 1) * 32;
      #pragma unroll
      for (int t = 0; t < 4; ++t) {
        aF[nxt][t] = *(const s16x8*)(aP[t] + off);
        bF[nxt][t] = *(const s16x8*)(bP[t] + off);
      }
    }
    #pragma unroll
    for (int mt = 0; mt < 4; ++mt)
      #pragma unroll
      for (int nt = 0; nt < 4; ++nt)
        acc[mt][nt] = __builtin_amdgcn_mfma_f32_16x16x32_bf16(aF[cur][mt], bF[cur][nt], acc[mt][nt], 0, 0, 0);
  }

  __syncthreads();   // LDS zeroing (done long ago) visible to all waves

  // ---- epilogue ----
  // acc[mt][nt][r] = sim[row = I + wm*64 + mt*16 + q*4 + r][col = J + wn*64 + 4*c16 + nt]
  #pragma unroll
  for (int mt = 0; mt < 4; ++mt)
    #pragma unroll
    for (int nt = 0; nt < 4; ++nt)
      #pragma unroll
      for (int r = 0; r < 4; ++r)
        acc[mt][nt][r] = __expf(acc[mt][nt][r] * INV_T - INV_T);

  const bool hasdiag = (bi == bj) && (wm == wn);
  const int cb = wn * 64 + 4 * c16;            // local col base (this lane's int4)

  // direct pass: rows I.., cols J..
  #pragma unroll
  for (int mt = 0; mt < 4; ++mt) {
    const int rl = wm * 64 + mt * 16 + q * 4;  // local row base
    i32x4 pv[4], nv[4];
    #pragma unroll
    for (int r = 0; r < 4; ++r) {
      const size_t off = (size_t)(I + rl + r) * NN + J + cb;
      pv[r] = __builtin_nontemporal_load((const i32x4*)(posm + off));
      nv[r] = __builtin_nontemporal_load((const i32x4*)(negm + off));
    }
    #pragma unroll
    for (int r = 0; r < 4; ++r) {
      float dsp = 0.f, dsn = 0.f, dpc = 0.f;
      #pragma unroll
      for (int nt = 0; nt < 4; ++nt) {
        float pf = (float)pv[r][nt];
        float nf = (float)nv[r][nt];
        if (hasdiag && (rl + r == cb + nt)) { pf = 0.f; nf = 0.f; }  // self-contrast diag
        const float e = acc[mt][nt][r];
        dsp = fmaf(e, pf, dsp);
        dsn = fmaf(e, nf, dsn);
        dpc += pf;
      }
      #pragma unroll
      for (int o = 1; o <= 8; o <<= 1) {
        dsp += __shfl_xor(dsp, o);
        dsn += __shfl_xor(dsn, o);
        dpc += __shfl_xor(dpc, o);
      }
      if (c16 == 0) {   // LDS atomics: lgkmcnt only, never stalls later vmem
        atomicAdd(&sacc[0][rl + r][0], dsp);
        atomicAdd(&sacc[0][rl + r][1], dsn);
        atomicAdd(&sacc[0][rl + r][2], dpc);
      }
    }
  }

  // transposed pass: sim(col,row) == sim(row,col); rows J.., cols I..
  if (offdiag) {
    #pragma unroll
    for (int nt = 0; nt < 4; ++nt) {
      const int trl = cb + nt;                 // local row in J-panel
      i32x4 pv[4], nv[4];
      #pragma unroll
      for (int mt = 0; mt < 4; ++mt) {
        const size_t off = (size_t)(J + trl) * NN + I + wm * 64 + mt * 16 + q * 4;
        pv[mt] = __builtin_nontemporal_load((const i32x4*)(posm + off));
        nv[mt] = __builtin_nontemporal_load((const i32x4*)(negm + off));
      }
      float ts = 0.f, tn = 0.f, tp = 0.f;
      #pragma unroll
      for (int mt = 0; mt < 4; ++mt) {
        #pragma unroll
        for (int r = 0; r < 4; ++r) {
          const float e = acc[mt][nt][r];
          ts = fmaf(e, (float)pv[mt][r], ts);
          tn = fmaf(e, (float)nv[mt][r], tn);
          tp += (float)pv[mt][r];
        }
      }
      ts += __shfl_xor(ts, 16); ts += __shfl_xor(ts, 32);
      tn += __shfl_xor(tn, 16); tn += __shfl_xor(tn, 32);
      tp += __shfl_xor(tp, 16); tp += __shfl_xor(tp, 32);
      if (q == 0) {
        atomicAdd(&sacc[1][trl][0], ts);
        atomicAdd(&sacc[1][trl][1], tn);
        atomicAdd(&sacc[1][trl][2], tp);
      }
    }
  }

  __syncthreads();

  // ---- final: one batch of global atomics, nothing issues after them ----
  const int r = tid & 127;
  if (tid < 128) {
    atomicAdd(&Spos[I + r], sacc[0][r][0]);
    atomicAdd(&Sneg[I + r], sacc[0][r][1]);
    atomicAdd(&Pcnt[I + r], sacc[0][r][2]);
  } else if (offdiag) {
    atomicAdd(&Spos[J + r], sacc[1][r][0]);
    atomicAdd(&Sneg[J + r], sacc[1][r][1]);
    atomicAdd(&Pcnt[J + r], sacc[1][r][2]);
  }
}

// ---------------- Kernel C: finalize ----------------
__global__ __launch_bounds__(256) void finalize_kernel(const float* __restrict__ Spos,
                                                       const float* __restrict__ Sneg,
                                                       const float* __restrict__ Pcnt,
                                                       float* __restrict__ out) {
  float local = 0.f;
  for (int i = threadIdx.x; i < NN; i += 256) {
    const float sp = Spos[i], sn = Sneg[i], pc = Pcnt[i];
    const float card = (pc == 0.f) ? 1.f : pc;
    // loss_i = -(sp - log(sn)*pc)/card
    local += (logf(sn) * pc - sp) / card;
  }
  #pragma unroll
  for (int o = 32; o; o >>= 1) local += __shfl_xor(local, o);
  __shared__ float red[4];
  if ((threadIdx.x & 63) == 0) red[threadIdx.x >> 6] = local;
  __syncthreads();
  if (threadIdx.x == 0)
    out[0] = (red[0] + red[1] + red[2] + red[3]) * (1.0f / (float)NN);
}

extern "C" void kernel_launch(void* const* d_in, const int* in_sizes, int n_in,
                              void* d_out, int out_size, void* d_ws, size_t ws_size,
                              hipStream_t stream) {
  const float* feat = (const float*)d_in[0];
  const int* posm   = (const int*)d_in[1];
  const int* negm   = (const int*)d_in[2];
  float* out = (float*)d_out;

  char* ws = (char*)d_ws;
  unsigned short* fnb = (unsigned short*)ws;                 // 8 MB
  float* Spos = (float*)(ws + (size_t)8 * 1024 * 1024);
  float* Sneg = Spos + NN;
  float* Pcnt = Sneg + NN;

  hipMemsetAsync(Spos, 0, 3 * NN * sizeof(float), stream);
  normalize_kernel<<<NN / 4, 256, 0, stream>>>(feat, fnb);
  fused_kernel<<<2080, 256, 0, stream>>>(fnb, posm, negm, Spos, Sneg, Pcnt);
  finalize_kernel<<<1, 256, 0, stream>>>(Spos, Sneg, Pcnt, out);
}